// Round 7
// baseline (215.848 us; speedup 1.0000x reference)
//
#include <hip/hip_runtime.h>

// Problem: B=64, C=16, H=32, W=512, SHIFT=4 (9 offsets), MARGIN=0.15
#define NB 64
#define NC 16
#define NH 32
#define NW 512
#define HW (NH * NW)      // 16384
#define CHW (NC * HW)     // 262144
#define NOFF 9
#define NCPB 4            // channels per block

// ws layout (floats): num_ap[64*9] | num_an[64*9] | cnt_ap[64*9] | cnt_an[64*9]
#define WS_NUM_AP 0
#define WS_NUM_AN 576
#define WS_CNT_AP 1152
#define WS_CNT_AN 1728
#define WS_FLOATS 2304

__device__ __forceinline__ float wave_sum_f(float v) {
#pragma unroll
    for (int o = 32; o > 0; o >>= 1) v += __shfl_down(v, o, 64);
    return v;
}

// grid: (8, 8, 64).
//   blockIdx.x: row tile (4 waves/block, each wave owns ONE row: 64 lanes x 8 floats = W)
//   blockIdx.y: bit0 = pair (0: a-p, 1: a-n), bits1-2 = channel group (4 ch each)
//   blockIdx.z: batch
//
// R4-R6 analysis: limiter is vector-memory REQUEST volume through the per-CU
// L1/TA path (R4: 604MB/82.6us, R6: 754MB/77.5us ~= same B/cy/CU; occupancy
// doubling bought only -6%). Fix: wave-owns-row layout. Each lane loads its
// 8 unique floats of A and F once (8B/pos vs 16B/pos); the +/-4 shift window
// comes from __shfl(lane+/-1) of the PRE-MASKED values (LDS pipe, off the
// global port). Row circularity == lane circularity, exact.
// Factorization unchanged (verified R4): with a'=m1*a, f'=m2*f,
//   sum_c m1*m2*(a-f_s)^2 = m2[k]*sa2'[j] + m1[j]*sf2'[k] - 2*crS[s],
// 25 accumulators (sa2[8]+sf2[8]+crS[9]); sf2/m2 windows rebuilt once in the
// epilogue via 16 shuffles.
__global__ __launch_bounds__(256, 4) void num_kernel(
    const float* __restrict__ a, const float* __restrict__ p,
    const float* __restrict__ n, const int* __restrict__ ma,
    const int* __restrict__ mp, const int* __restrict__ mn,
    float* __restrict__ ws)
{
    const int b    = blockIdx.z;
    const int pair = blockIdx.y & 1;        // 0 -> p, 1 -> n
    const int cg   = blockIdx.y >> 1;       // channel group: 0..3
    const int lane = threadIdx.x & 63;
    const int wid  = threadIdx.x >> 6;
    const int row  = blockIdx.x * 4 + wid;  // 0..31
    const int base = row * NW + lane * 8;   // element offset in an HW plane
    const int prevL = (lane + 63) & 63;     // lane-1 (row-circular)
    const int nextL = (lane + 1)  & 63;     // lane+1 (row-circular)

    // ---- masks: 4 int4 loads, once per block ----
    const int* MA = ma + b * HW + base;
    const int* M2 = (pair ? mn : mp) + b * HW + base;
    int4 ma0 = *(const int4*)(MA);
    int4 ma1 = *(const int4*)(MA + 4);
    int4 mb0 = *(const int4*)(M2);
    int4 mb1 = *(const int4*)(M2 + 4);

    float m1f[8] = {ma0.x ? 1.f : 0.f, ma0.y ? 1.f : 0.f, ma0.z ? 1.f : 0.f, ma0.w ? 1.f : 0.f,
                    ma1.x ? 1.f : 0.f, ma1.y ? 1.f : 0.f, ma1.z ? 1.f : 0.f, ma1.w ? 1.f : 0.f};
    float m2f[8] = {mb0.x ? 1.f : 0.f, mb0.y ? 1.f : 0.f, mb0.z ? 1.f : 0.f, mb0.w ? 1.f : 0.f,
                    mb1.x ? 1.f : 0.f, mb1.y ? 1.f : 0.f, mb1.z ? 1.f : 0.f, mb1.w ? 1.f : 0.f};

    const float* A = a + (size_t)b * CHW + (size_t)cg * NCPB * HW + base;
    const float* F = (pair ? n : p) + (size_t)b * CHW + (size_t)cg * NCPB * HW + base;

    float sa2[8], sf2[8], crS[NOFF];
#pragma unroll
    for (int j = 0; j < 8; ++j) { sa2[j] = 0.f; sf2[j] = 0.f; }
#pragma unroll
    for (int s = 0; s < NOFF; ++s) crS[s] = 0.f;

    // ---- channel loop: 4 float4 loads (unique bytes only) + 8 shuffles + ~104 FMA ----
#pragma unroll 2
    for (int c = 0; c < NCPB; ++c) {
        const float* Ac = A + c * HW;
        const float* Fc = F + c * HW;
        float4 a0 = *(const float4*)(Ac);
        float4 a1 = *(const float4*)(Ac + 4);
        float4 f0 = *(const float4*)(Fc);
        float4 f1 = *(const float4*)(Fc + 4);
        float av[8] = {a0.x, a0.y, a0.z, a0.w, a1.x, a1.y, a1.z, a1.w};
        float fv[8] = {f0.x, f0.y, f0.z, f0.w, f1.x, f1.y, f1.z, f1.w};

        float am[8], fm[8];
#pragma unroll
        for (int j = 0; j < 8; ++j) { am[j] = av[j] * m1f[j]; fm[j] = fv[j] * m2f[j]; }

        // window wfm[t] = premasked F at position (base + t - 4), t in [0,16)
        float wfm[16];
#pragma unroll
        for (int i = 0; i < 4; ++i) wfm[i]      = __shfl(fm[4 + i], prevL, 64);
#pragma unroll
        for (int i = 0; i < 8; ++i) wfm[4 + i]  = fm[i];
#pragma unroll
        for (int i = 0; i < 4; ++i) wfm[12 + i] = __shfl(fm[i], nextL, 64);

#pragma unroll
        for (int j = 0; j < 8; ++j) sa2[j] = fmaf(am[j], am[j], sa2[j]);
#pragma unroll
        for (int j = 0; j < 8; ++j) sf2[j] = fmaf(fm[j], fm[j], sf2[j]);
#pragma unroll
        for (int s = 0; s < NOFF; ++s) {
#pragma unroll
            for (int j = 0; j < 8; ++j) {
                crS[s] = fmaf(am[j], wfm[j + 8 - s], crS[s]);  // f2 pos = j+4-s
            }
        }
    }

    // ---- epilogue: rebuild sf2/m2 windows once, apply mask coefficients ----
    float sf2w[16], m2w[16];
#pragma unroll
    for (int i = 0; i < 4; ++i) {
        sf2w[i]      = __shfl(sf2[4 + i], prevL, 64);
        m2w[i]       = __shfl(m2f[4 + i], prevL, 64);
    }
#pragma unroll
    for (int i = 0; i < 8; ++i) { sf2w[4 + i] = sf2[i]; m2w[4 + i] = m2f[i]; }
#pragma unroll
    for (int i = 0; i < 4; ++i) {
        sf2w[12 + i] = __shfl(sf2[i], nextL, 64);
        m2w[12 + i]  = __shfl(m2f[i], nextL, 64);
    }

    float sx[NOFF], cxf[NOFF];
#pragma unroll
    for (int s = 0; s < NOFF; ++s) {
        float t = 0.f, cc = 0.f;
#pragma unroll
        for (int j = 0; j < 8; ++j) {
            const int k = j + 8 - s;
            t  = fmaf(m2w[k], sa2[j], t);
            t  = fmaf(m1f[j], sf2w[k], t);
            cc = fmaf(m1f[j], m2w[k], cc);
        }
        sx[s]  = fmaf(-2.f, crS[s], t);
        cxf[s] = cc;
    }

    // ---- wave reduce -> LDS -> block reduce -> few atomics per block ----
    __shared__ float red[4][20];           // [wave][9 num + 9 cnt], padded
#pragma unroll
    for (int s = 0; s < NOFF; ++s) sx[s] = wave_sum_f(sx[s]);
    if (cg == 0) {
#pragma unroll
        for (int s = 0; s < NOFF; ++s) cxf[s] = wave_sum_f(cxf[s]);
    }
    if (lane == 0) {
#pragma unroll
        for (int s = 0; s < NOFF; ++s) {
            red[wid][s] = sx[s];
            red[wid][9 + s] = cxf[s];
        }
    }
    __syncthreads();

    float* numws = ws + (pair ? WS_NUM_AN : WS_NUM_AP) + b * NOFF;
    float* cntws = ws + (pair ? WS_CNT_AN : WS_CNT_AP) + b * NOFF;
    const int i = threadIdx.x;
    if (i < 9) {
        float v = red[0][i] + red[1][i] + red[2][i] + red[3][i];
        atomicAdd(numws + i, v);
    } else if (i < 18 && cg == 0) {
        float v = red[0][i] + red[1][i] + red[2][i] + red[3][i];
        atomicAdd(cntws + (i - 9), v);
    }
}

// 1 block, 64 threads: thread b handles batch b; wave-reduce the mean.
__global__ void finish_kernel(const float* __restrict__ ws, float* __restrict__ out)
{
    const int b = threadIdx.x;   // 0..63
    const float* num_ap = ws + WS_NUM_AP;
    const float* num_an = ws + WS_NUM_AN;
    const float* cnt_ap = ws + WS_CNT_AP;
    const float* cnt_an = ws + WS_CNT_AN;

    float ap = 3.4e38f, an = 3.4e38f;
#pragma unroll
    for (int s = 0; s < NOFF; ++s) {
        ap = fminf(ap, num_ap[b * NOFF + s] / (16.f * cnt_ap[b * NOFF + s] + 0.001f));
        an = fminf(an, num_an[b * NOFF + s] / (16.f * cnt_an[b * NOFF + s] + 0.001f));
    }
    float loss = fmaxf(ap - an + 0.15f, 0.f);
    loss = wave_sum_f(loss);
    if (b == 0) out[0] = loss * (1.0f / 64.f);
}

extern "C" void kernel_launch(void* const* d_in, const int* in_sizes, int n_in,
                              void* d_out, int out_size, void* d_ws, size_t ws_size,
                              hipStream_t stream) {
    const float* a = (const float*)d_in[0];
    const float* p = (const float*)d_in[1];
    const float* n = (const float*)d_in[2];
    const int* ma = (const int*)d_in[3];
    const int* mp = (const int*)d_in[4];
    const int* mn = (const int*)d_in[5];
    float* ws = (float*)d_ws;
    float* out = (float*)d_out;

    // ws is poisoned 0xAA before every timed launch — zero the accumulators.
    hipMemsetAsync(d_ws, 0, WS_FLOATS * sizeof(float), stream);

    num_kernel<<<dim3(8, 8, NB), 256, 0, stream>>>(a, p, n, ma, mp, mn, ws);
    finish_kernel<<<1, 64, 0, stream>>>(ws, out);
}